// Round 13
// baseline (117.294 us; speedup 1.0000x reference)
//
#include <hip/hip_runtime.h>

// ScaledDotProductAttention: causal cosine attention.
// B=4 H=16 N=2048 D=64, fp32 in/out, bf16 MFMA compute.
//
// Round 13: r10 structure, but V is NEVER staged to LDS. The V-tile (8 KB,
// tiled layout) is read by all 8 waves -> L1-resident after first touch;
// vf comes straight from global. LDS holds only K (3x8KB triple buffer).
// r12 audit: LDS-read pipe was ~30 us (128 KB/block-iter + 4.3M conflict
// cycles) -- the largest pipe; this halves it at zero VGPR cost (r11's
// register approach hit 164 VGPR and died).
//  - QBLK=256 (8 waves x 32 q-rows), KVBLK=64, grid 512 = 2 blocks/CU,
//    heavy-first (r10 mapping; r12's pairing was worse).
//  - K pre-swizzled (elem ^= (row&7)<<3), gload_lds(16B), counted vmcnt
//    (2/1/0), raw s_barriers.
//  - no-max softmax: scores cosine-bounded (|s| <= g*log2e ~31.7), so
//    p = exp2(s) directly -- exact by shift-invariance.
//  - swapped-operand MFMA, cvt_pk + permlane32_swap P repack.

#define BATCH 4
#define HEADS 16
#define SEQ   2048
#define DIM   64
#define EPS   1e-8f
#define LOG2E 1.44269504088896340736f

typedef short bf16x8 __attribute__((ext_vector_type(8)));
typedef short s16x4  __attribute__((ext_vector_type(4)));
typedef float fx16   __attribute__((ext_vector_type(16)));
typedef unsigned int u32x4 __attribute__((ext_vector_type(4)));

static __device__ __forceinline__ short f2bf(float x) {
    unsigned u = __float_as_uint(x);
    unsigned r = (u + 0x7fffu + ((u >> 16) & 1u)) >> 16;   // RNE
    return (short)r;
}
static __device__ __forceinline__ unsigned cvt_pk(float lo, float hi) {
    unsigned r;
    asm("v_cvt_pk_bf16_f32 %0, %1, %2" : "=v"(r) : "v"(lo), "v"(hi));
    return r;
}
static __device__ __forceinline__ void gload_lds16(const short* g, short* l) {
    __builtin_amdgcn_global_load_lds(
        (const __attribute__((address_space(1))) void*)g,
        (__attribute__((address_space(3))) void*)l, 16, 0, 0);
}

// ---------------------------------------------------------------------------
// Kernel 1: K rows -> L2-normalized bf16, tiled+swizzled layout:
// Kn[bh][kt][r][e ^ ((r&7)<<3)] = Khat[bh][kt*64+r][e]
// ---------------------------------------------------------------------------
__global__ __launch_bounds__(256) void norm_k(
    const float* __restrict__ K, short* __restrict__ Kn)
{
    const int tid  = threadIdx.x;
    const int lane = tid & 63;
    long long rid = (long long)blockIdx.x * 16 + (tid >> 6) * 4 + (lane >> 4);
    const int c4 = (lane & 15) * 4;

    const float* src = K + rid * DIM;
    float4 v = *(const float4*)(src + c4);
    float ss = v.x * v.x + v.y * v.y + v.z * v.z + v.w * v.w;
    ss += __shfl_xor(ss, 1);
    ss += __shfl_xor(ss, 2);
    ss += __shfl_xor(ss, 4);
    ss += __shfl_xor(ss, 8);
    float s = 1.0f / (sqrtf(ss) + EPS);

    const int bh = (int)(rid >> 11);
    const int n  = (int)(rid & 2047);
    const int kt = n >> 6;
    const int r  = n & 63;
    short* dst = Kn + ((size_t)bh << 17) + (kt << 12) + (r << 6);

    s16x4 o;
    o[0] = f2bf(v.x * s);
    o[1] = f2bf(v.y * s);
    o[2] = f2bf(v.z * s);
    o[3] = f2bf(v.w * s);
    *(s16x4*)(dst + (c4 ^ ((r & 7) << 3))) = o;
}

// ---------------------------------------------------------------------------
// Kernel 2: V [n][d] fp32 -> Vt tiled bf16 (NO swizzle -- read via L1):
// Vt[bh][kt][d][k'] = V[bh][kt*64+k'][d]
// ---------------------------------------------------------------------------
#define TLDS 68

__global__ __launch_bounds__(256) void transpose_v(
    const float* __restrict__ V, short* __restrict__ Vt)
{
    const int nt = blockIdx.x;
    const int bh = blockIdx.y;
    const float* Vb = V + ((size_t)bh * SEQ + (size_t)nt * 64) * DIM;
    short* Vo = Vt + ((size_t)bh << 17) + (nt << 12);

    __shared__ short lds[DIM * TLDS];
    const int t  = threadIdx.x;
    const int cg = t & 15;
    const int rr = t >> 4;

#pragma unroll
    for (int i = 0; i < 4; ++i) {
        int n  = rr + i * 16;
        int d0 = cg * 4;
        float4 v = *(const float4*)(Vb + (size_t)n * DIM + d0);
        lds[(d0 + 0) * TLDS + n] = f2bf(v.x);
        lds[(d0 + 1) * TLDS + n] = f2bf(v.y);
        lds[(d0 + 2) * TLDS + n] = f2bf(v.z);
        lds[(d0 + 3) * TLDS + n] = f2bf(v.w);
    }
    __syncthreads();
#pragma unroll
    for (int i = 0; i < 4; ++i) {
        int d  = rr + i * 16;
        int nl = cg * 4;
        s16x4 o;
        o[0] = lds[d * TLDS + nl + 0];
        o[1] = lds[d * TLDS + nl + 1];
        o[2] = lds[d * TLDS + nl + 2];
        o[3] = lds[d * TLDS + nl + 3];
        *(s16x4*)(Vo + (d << 6) + nl) = o;
    }
}

// ---------------------------------------------------------------------------
// Kernel 3: flash attention. 512 threads = 8 waves, QBLK=256, KVBLK=64.
// K: LDS triple-buffer (one gload_lds per tile), counted vmcnt (2/1/0).
// V: direct global reads from tiled Vt (L1-resident, shared by 8 waves).
//
// mfma_f32_32x32x16_bf16 layouts:
//   A: row = lane&31, k = (lane>>5)*8 + j
//   B: col = lane&31, k = (lane>>5)*8 + j
//   C/D: col = lane&31, row = (reg&3) + 8*(reg>>2) + 4*(lane>>5)
// ---------------------------------------------------------------------------
__global__ __launch_bounds__(512) void attn_fwd(
    const float* __restrict__ Q, const float* __restrict__ scale,
    const short* __restrict__ Kn, const short* __restrict__ Vt,
    float* __restrict__ out)
{
    const int lid = blockIdx.x;                       // 0..511
    const int bh  = (lid & 7) * 8 + ((lid >> 3) & 7); // XCD lid%8 owns bh/8
    const int qb  = 7 - (lid >> 6);                   // heavy q-blocks first
    const int tid = threadIdx.x;
    const int w   = tid >> 6;                         // wave 0..7
    const int l   = tid & 63;
    const int lq  = l & 31;
    const int hi  = l >> 5;

    const short* Kb = Kn + ((size_t)bh << 17);
    const short* Vb = Vt + ((size_t)bh << 17);
    const float  g  = scale[bh & (HEADS - 1)];

    __shared__ __align__(16) short ldsK[3][64 * 64];

    const int toff = tid * 8;   // 512 thr x 8 shorts = full 4096-short tile

    const int wlo  = qb * 256 + w * 32;   // wave's first q-row
    const int whi  = wlo + 31;
    const int qrow = wlo + lq;
    const int nkt  = 4 * qb + 4;

    // ---- prologue: stage K tiles 0 and 1 ----
    gload_lds16(Kb + toff,        &ldsK[0][toff]);
    gload_lds16(Kb + 4096 + toff, &ldsK[1][toff]);

    // ---- fused Q-norm (overlaps stage latency; its own loads are consumed
    //      here, before the steady loop) ----
    const float* Qrow = Q + ((size_t)bh * SEQ + qrow) * DIM;
    float qv[4][8];
    float ss = 0.f;
#pragma unroll
    for (int c = 0; c < 4; ++c) {
        float4 a = *(const float4*)(Qrow + c * 16 + hi * 8);
        float4 b = *(const float4*)(Qrow + c * 16 + hi * 8 + 4);
        qv[c][0] = a.x; qv[c][1] = a.y; qv[c][2] = a.z; qv[c][3] = a.w;
        qv[c][4] = b.x; qv[c][5] = b.y; qv[c][6] = b.z; qv[c][7] = b.w;
#pragma unroll
        for (int jj = 0; jj < 8; ++jj) ss += qv[c][jj] * qv[c][jj];
    }
    ss += __shfl_xor(ss, 32);
    const float sc = g * LOG2E / (sqrtf(ss) + EPS);

    bf16x8 qbf[4];
#pragma unroll
    for (int c = 0; c < 4; ++c) {
        u32x4 wds;
#pragma unroll
        for (int m = 0; m < 4; ++m)
            wds[m] = cvt_pk(qv[c][2 * m] * sc, qv[c][2 * m + 1] * sc);
        qbf[c] = __builtin_bit_cast(bf16x8, wds);
    }

    fx16 oacc[2];
#pragma unroll
    for (int dt = 0; dt < 2; ++dt)
#pragma unroll
        for (int r = 0; r < 16; ++r) oacc[dt][r] = 0.f;
    float lsum = 0.f;

    int cur = 0;   // kt % 3
    for (int kt = 0; kt < nkt; ++kt) {
        // bar A: every wave finished compute(kt-1); buf[(kt+2)%3] is free.
        __builtin_amdgcn_s_barrier();

        if (kt + 2 < nkt) {
            int nb = cur + 2; if (nb >= 3) nb -= 3;
            gload_lds16(Kb + (size_t)(kt + 2) * 4096 + toff, &ldsK[nb][toff]);
            // own stage(kt) landed; stages (kt+1),(kt+2) stay in flight.
            // (vf loads of prior iterations were consumed by their MFMAs.)
            asm volatile("s_waitcnt vmcnt(2)" ::: "memory");
        } else if (kt + 1 < nkt) {
            asm volatile("s_waitcnt vmcnt(1)" ::: "memory");
        } else {
            asm volatile("s_waitcnt vmcnt(0)" ::: "memory");
        }
        // bar B: all waves' stage(kt) slices visible
        __builtin_amdgcn_s_barrier();

        const int k0 = kt * 64;
        if (k0 <= whi) {   // wave-uniform causal skip (barriers outside)
            const short* lk = ldsK[cur];

            // ---- K frags from LDS (swizzled), S' = K x Q^T ----
            fx16 sacc[2];
#pragma unroll
            for (int t = 0; t < 2; ++t)
#pragma unroll
                for (int r = 0; r < 16; ++r) sacc[t][r] = 0.f;

            bf16x8 kf[2][4];
#pragma unroll
            for (int t = 0; t < 2; ++t)
#pragma unroll
                for (int c = 0; c < 4; ++c) {
                    int r = t * 32 + lq;
                    kf[t][c] = *(const bf16x8*)
                        &lk[(r << 6) + ((c * 16 + hi * 8) ^ ((r & 7) << 3))];
                }
            __builtin_amdgcn_s_setprio(1);
#pragma unroll
            for (int c = 0; c < 4; ++c) {
                sacc[0] = __builtin_amdgcn_mfma_f32_32x32x16_bf16(kf[0][c], qbf[c], sacc[0], 0, 0, 0);
                sacc[1] = __builtin_amdgcn_mfma_f32_32x32x16_bf16(kf[1][c], qbf[c], sacc[1], 0, 0, 0);
            }
            __builtin_amdgcn_s_setprio(0);

            // ---- V frags DIRECT from global tiled Vt (L1-shared) ----
            const short* vtile = Vb + (size_t)kt * 4096;
            bf16x8 vf[2][4];
#pragma unroll
            for (int dt = 0; dt < 2; ++dt)
#pragma unroll
                for (int ks = 0; ks < 4; ++ks) {
                    int d = dt * 32 + lq;
                    vf[dt][ks] = *(const bf16x8*)
                        (vtile + (d << 6) + ks * 16 + hi * 8);
                }

            float pv[32];
#pragma unroll
            for (int t = 0; t < 2; ++t)
#pragma unroll
                for (int r = 0; r < 16; ++r) pv[t * 16 + r] = sacc[t][r];

            // ---- causal mask: only the wave's diagonal tile ----
            if (k0 + 63 > wlo) {
#pragma unroll
                for (int t = 0; t < 2; ++t)
#pragma unroll
                    for (int r = 0; r < 16; ++r) {
                        int key = k0 + 32 * t + (r & 3) + 8 * (r >> 2) + 4 * hi;
                        if (key > qrow) pv[t * 16 + r] = -3.0e38f;
                    }
            }

            // ---- p = exp2(s) (cosine-bounded, no max shift) ----
#pragma unroll
            for (int r = 0; r < 32; ++r)
                pv[r] = __builtin_amdgcn_exp2f(pv[r]);

            // ---- lsum += row sum ----
            float ts[16];
#pragma unroll
            for (int r = 0; r < 16; ++r) ts[r] = pv[r] + pv[r + 16];
#pragma unroll
            for (int r = 0; r < 8; ++r) ts[r] += ts[r + 8];
#pragma unroll
            for (int r = 0; r < 4; ++r) ts[r] += ts[r + 4];
            float ps = (ts[0] + ts[1]) + (ts[2] + ts[3]);
            ps += __shfl_xor(ps, 32);
            lsum += ps;

            // ---- repack P -> B-fragments via v_permlane32_swap_b32 ----
            u32x4 paw[4];
#pragma unroll
            for (int ks = 0; ks < 4; ++ks) {
                const int t = ks >> 1;
                const int b0 = (ks & 1) * 8;
#pragma unroll
                for (int m = 0; m < 2; ++m) {
                    unsigned a = cvt_pk(pv[t * 16 + b0 + 2 * m], pv[t * 16 + b0 + 2 * m + 1]);
                    unsigned b = cvt_pk(pv[t * 16 + b0 + 2 * m + 4], pv[t * 16 + b0 + 2 * m + 5]);
                    asm("v_permlane32_swap_b32 %0, %1" : "+v"(a), "+v"(b));
                    paw[ks][m]     = a;
                    paw[ks][m + 2] = b;
                }
            }

            // ---- O' += Vt x P ----
            __builtin_amdgcn_s_setprio(1);
#pragma unroll
            for (int dt = 0; dt < 2; ++dt)
#pragma unroll
                for (int ks = 0; ks < 4; ++ks) {
                    bf16x8 pa = __builtin_bit_cast(bf16x8, paw[ks]);
                    oacc[dt] = __builtin_amdgcn_mfma_f32_32x32x16_bf16(vf[dt][ks], pa, oacc[dt], 0, 0, 0);
                }
            __builtin_amdgcn_s_setprio(0);
        }
        cur = (cur == 2) ? 0 : cur + 1;
    }

    // ---- epilogue: out[q][d] = O'/lsum ----
    float inv = 1.0f / lsum;
    size_t rb = ((size_t)bh * SEQ + (size_t)qrow) * DIM;
#pragma unroll
    for (int dt = 0; dt < 2; ++dt)
#pragma unroll
        for (int g4 = 0; g4 < 4; ++g4) {
            float4 o4;
            o4.x = oacc[dt][4 * g4 + 0] * inv;
            o4.y = oacc[dt][4 * g4 + 1] * inv;
            o4.z = oacc[dt][4 * g4 + 2] * inv;
            o4.w = oacc[dt][4 * g4 + 3] * inv;
            *(float4*)(out + rb + dt * 32 + 8 * g4 + 4 * hi) = o4;
        }
}

// ---------------------------------------------------------------------------
extern "C" void kernel_launch(void* const* d_in, const int* in_sizes, int n_in,
                              void* d_out, int out_size, void* d_ws, size_t ws_size,
                              hipStream_t stream)
{
    const float* Q  = (const float*)d_in[0];
    const float* K  = (const float*)d_in[1];
    const float* V  = (const float*)d_in[2];
    const float* qs = (const float*)d_in[3];
    float* out = (float*)d_out;

    const size_t nElem = (size_t)BATCH * HEADS * SEQ * DIM;
    short* Kn = (short*)d_ws;
    short* Vt = Kn + nElem;

    {
        long long rows = (long long)BATCH * HEADS * SEQ;
        norm_k<<<(int)(rows / 16), 256, 0, stream>>>(K, Kn);
    }
    {
        dim3 grid(SEQ / 64, BATCH * HEADS);
        transpose_v<<<grid, 256, 0, stream>>>(V, Vt);
    }
    {
        // 512 blocks = 2/CU: XCD lid%8 owns bh chunk; 8 q-blocks per bh
        attn_fwd<<<(SEQ / 256) * BATCH * HEADS, 512, 0, stream>>>(Q, qs, Kn, Vt, out);
    }
}

// Round 14
// 83.555 us; speedup vs baseline: 1.4038x; 1.4038x over previous
//
#include <hip/hip_runtime.h>

// ScaledDotProductAttention: causal cosine attention.
// B=4 H=16 N=2048 D=64, fp32 in/out, bf16 MFMA compute.
//
// Round 14: r10's proven inner loop (best: 68 us), residency fixes only:
//  - QBLK=128 (4 waves x 32 q-rows), grid 1024 = 4 blocks/CU in grid,
//    3 co-resident (LDS 48 KB/block; 144 <= 160 KB). r10's 512-block grid
//    hard-capped residency at 2/CU and had +-33% pair imbalance.
//  - Staging doubles to 295 MB ~ 8 B/cy/CU -- under the ~10.5 ceiling.
//  - K,V triple-buffered via global_load_lds(16B), counted vmcnt (8/4/0),
//    raw s_barriers; Kn/Vt pre-swizzled (elem ^= (row&7)<<3 per 64x64 tile).
//  - no-max softmax: scores cosine-bounded (|s| <= g*log2e ~31.7), so
//    p = exp2(s) directly -- exact by shift-invariance.
//  - swapped-operand MFMA, cvt_pk + permlane32_swap P repack.
// r13 lesson: V must stay in LDS -- 128B-stride global gather (even
// L1-resident) costs ~4x the LDS-read path it replaced.

#define BATCH 4
#define HEADS 16
#define SEQ   2048
#define DIM   64
#define EPS   1e-8f
#define LOG2E 1.44269504088896340736f

typedef short bf16x8 __attribute__((ext_vector_type(8)));
typedef short s16x4  __attribute__((ext_vector_type(4)));
typedef float fx16   __attribute__((ext_vector_type(16)));
typedef unsigned int u32x4 __attribute__((ext_vector_type(4)));

static __device__ __forceinline__ short f2bf(float x) {
    unsigned u = __float_as_uint(x);
    unsigned r = (u + 0x7fffu + ((u >> 16) & 1u)) >> 16;   // RNE
    return (short)r;
}
static __device__ __forceinline__ unsigned cvt_pk(float lo, float hi) {
    unsigned r;
    asm("v_cvt_pk_bf16_f32 %0, %1, %2" : "=v"(r) : "v"(lo), "v"(hi));
    return r;
}
static __device__ __forceinline__ void gload_lds16(const short* g, short* l) {
    __builtin_amdgcn_global_load_lds(
        (const __attribute__((address_space(1))) void*)g,
        (__attribute__((address_space(3))) void*)l, 16, 0, 0);
}

// ---------------------------------------------------------------------------
// Kernel 1: K rows -> L2-normalized bf16, tiled+swizzled layout:
// Kn[bh][kt][r][e ^ ((r&7)<<3)] = Khat[bh][kt*64+r][e]
// ---------------------------------------------------------------------------
__global__ __launch_bounds__(256) void norm_k(
    const float* __restrict__ K, short* __restrict__ Kn)
{
    const int tid  = threadIdx.x;
    const int lane = tid & 63;
    long long rid = (long long)blockIdx.x * 16 + (tid >> 6) * 4 + (lane >> 4);
    const int c4 = (lane & 15) * 4;

    const float* src = K + rid * DIM;
    float4 v = *(const float4*)(src + c4);
    float ss = v.x * v.x + v.y * v.y + v.z * v.z + v.w * v.w;
    ss += __shfl_xor(ss, 1);
    ss += __shfl_xor(ss, 2);
    ss += __shfl_xor(ss, 4);
    ss += __shfl_xor(ss, 8);
    float s = 1.0f / (sqrtf(ss) + EPS);

    const int bh = (int)(rid >> 11);
    const int n  = (int)(rid & 2047);
    const int kt = n >> 6;
    const int r  = n & 63;
    short* dst = Kn + ((size_t)bh << 17) + (kt << 12) + (r << 6);

    s16x4 o;
    o[0] = f2bf(v.x * s);
    o[1] = f2bf(v.y * s);
    o[2] = f2bf(v.z * s);
    o[3] = f2bf(v.w * s);
    *(s16x4*)(dst + (c4 ^ ((r & 7) << 3))) = o;
}

// ---------------------------------------------------------------------------
// Kernel 2: V [n][d] fp32 -> Vt tiled+swizzled bf16:
// Vt[bh][kt][d][k ^ ((d&7)<<3)] = V[bh][kt*64+k][d]
// ---------------------------------------------------------------------------
#define TLDS 68

__global__ __launch_bounds__(256) void transpose_v(
    const float* __restrict__ V, short* __restrict__ Vt)
{
    const int nt = blockIdx.x;
    const int bh = blockIdx.y;
    const float* Vb = V + ((size_t)bh * SEQ + (size_t)nt * 64) * DIM;
    short* Vo = Vt + ((size_t)bh << 17) + (nt << 12);

    __shared__ short lds[DIM * TLDS];
    const int t  = threadIdx.x;
    const int cg = t & 15;
    const int rr = t >> 4;

#pragma unroll
    for (int i = 0; i < 4; ++i) {
        int n  = rr + i * 16;
        int d0 = cg * 4;
        float4 v = *(const float4*)(Vb + (size_t)n * DIM + d0);
        lds[(d0 + 0) * TLDS + n] = f2bf(v.x);
        lds[(d0 + 1) * TLDS + n] = f2bf(v.y);
        lds[(d0 + 2) * TLDS + n] = f2bf(v.z);
        lds[(d0 + 3) * TLDS + n] = f2bf(v.w);
    }
    __syncthreads();
#pragma unroll
    for (int i = 0; i < 4; ++i) {
        int d  = rr + i * 16;
        int nl = cg * 4;
        s16x4 o;
        o[0] = lds[d * TLDS + nl + 0];
        o[1] = lds[d * TLDS + nl + 1];
        o[2] = lds[d * TLDS + nl + 2];
        o[3] = lds[d * TLDS + nl + 3];
        *(s16x4*)(Vo + (d << 6) + (nl ^ ((d & 7) << 3))) = o;
    }
}

// ---------------------------------------------------------------------------
// Kernel 3: flash attention. 256 threads = 4 waves, QBLK=128, KVBLK=64.
// Grid 1024 (16 qb x 64 bh), heavy-first; 3 blocks co-resident per CU.
// Triple-buffered stage 2 tiles ahead, counted vmcnt (8/4/0).
//
// mfma_f32_32x32x16_bf16 layouts:
//   A: row = lane&31, k = (lane>>5)*8 + j
//   B: col = lane&31, k = (lane>>5)*8 + j
//   C/D: col = lane&31, row = (reg&3) + 8*(reg>>2) + 4*(lane>>5)
// ---------------------------------------------------------------------------
__global__ __launch_bounds__(256) void attn_fwd(
    const float* __restrict__ Q, const float* __restrict__ scale,
    const short* __restrict__ Kn, const short* __restrict__ Vt,
    float* __restrict__ out)
{
    const int lid = blockIdx.x;                       // 0..1023
    const int bh  = (lid & 7) * 8 + ((lid >> 3) & 7); // XCD lid%8 owns bh/8
    const int qb  = 15 - (lid >> 6);                  // heavy q-blocks first
    const int tid = threadIdx.x;
    const int w   = tid >> 6;                         // wave 0..3
    const int l   = tid & 63;
    const int lq  = l & 31;
    const int hi  = l >> 5;

    const short* Kb = Kn + ((size_t)bh << 17);
    const short* Vb = Vt + ((size_t)bh << 17);
    const float  g  = scale[bh & (HEADS - 1)];

    __shared__ __align__(16) short ldsK[3][64 * 64];
    __shared__ __align__(16) short ldsV[3][64 * 64];

    const int toff = tid * 8;   // 256 thr x 8 shorts = 2048 shorts per gload

    const int wlo  = qb * 128 + w * 32;   // wave's first q-row
    const int whi  = wlo + 31;
    const int qrow = wlo + lq;
    const int nkt  = 2 * qb + 2;

    // ---- Q loads FIRST (oldest in vmcnt queue; compiler's wait for their
    //      use leaves the stage loads below in flight) ----
    const float* Qrow = Q + ((size_t)bh * SEQ + qrow) * DIM;
    float qv[4][8];
#pragma unroll
    for (int c = 0; c < 4; ++c) {
        float4 a = *(const float4*)(Qrow + c * 16 + hi * 8);
        float4 b = *(const float4*)(Qrow + c * 16 + hi * 8 + 4);
        qv[c][0] = a.x; qv[c][1] = a.y; qv[c][2] = a.z; qv[c][3] = a.w;
        qv[c][4] = b.x; qv[c][5] = b.y; qv[c][6] = b.z; qv[c][7] = b.w;
    }

    // ---- prologue: stage tiles 0 and 1 ----
    gload_lds16(Kb + toff,        &ldsK[0][toff]);
    gload_lds16(Kb + 2048 + toff, &ldsK[0][2048 + toff]);
    gload_lds16(Vb + toff,        &ldsV[0][toff]);
    gload_lds16(Vb + 2048 + toff, &ldsV[0][2048 + toff]);
    gload_lds16(Kb + 4096 + toff, &ldsK[1][toff]);
    gload_lds16(Kb + 6144 + toff, &ldsK[1][2048 + toff]);
    gload_lds16(Vb + 4096 + toff, &ldsV[1][toff]);
    gload_lds16(Vb + 6144 + toff, &ldsV[1][2048 + toff]);

    // ---- fused Q-norm (overlaps stage latency) ----
    float ss = 0.f;
#pragma unroll
    for (int c = 0; c < 4; ++c)
#pragma unroll
        for (int jj = 0; jj < 8; ++jj) ss += qv[c][jj] * qv[c][jj];
    ss += __shfl_xor(ss, 32);
    const float sc = g * LOG2E / (sqrtf(ss) + EPS);

    bf16x8 qbf[4];
#pragma unroll
    for (int c = 0; c < 4; ++c) {
        u32x4 wds;
#pragma unroll
        for (int m = 0; m < 4; ++m)
            wds[m] = cvt_pk(qv[c][2 * m] * sc, qv[c][2 * m + 1] * sc);
        qbf[c] = __builtin_bit_cast(bf16x8, wds);
    }

    fx16 oacc[2];
#pragma unroll
    for (int dt = 0; dt < 2; ++dt)
#pragma unroll
        for (int r = 0; r < 16; ++r) oacc[dt][r] = 0.f;
    float lsum = 0.f;

    int cur = 0;   // kt % 3
    for (int kt = 0; kt < nkt; ++kt) {
        // bar A: every wave finished compute(kt-1); buf[(kt+2)%3] is free.
        __builtin_amdgcn_s_barrier();

        if (kt + 2 < nkt) {
            int nb = cur + 2; if (nb >= 3) nb -= 3;
            const short* gK = Kb + (size_t)(kt + 2) * 4096;
            const short* gV = Vb + (size_t)(kt + 2) * 4096;
            gload_lds16(gK + toff,        &ldsK[nb][toff]);
            gload_lds16(gK + 2048 + toff, &ldsK[nb][2048 + toff]);
            gload_lds16(gV + toff,        &ldsV[nb][toff]);
            gload_lds16(gV + 2048 + toff, &ldsV[nb][2048 + toff]);
            // own stage(kt) done; stages (kt+1),(kt+2) = 8 loads in flight
            asm volatile("s_waitcnt vmcnt(8)" ::: "memory");
        } else if (kt + 1 < nkt) {
            asm volatile("s_waitcnt vmcnt(4)" ::: "memory");
        } else {
            asm volatile("s_waitcnt vmcnt(0)" ::: "memory");
        }
        // bar B: all waves' stage(kt) slices visible
        __builtin_amdgcn_s_barrier();

        const int k0 = kt * 64;
        if (k0 <= whi) {   // wave-uniform causal skip (barriers outside)
            const short* lk = ldsK[cur];
            const short* lv = ldsV[cur];

            // ---- K frags from LDS (swizzled), S' = K x Q^T ----
            fx16 sacc[2];
#pragma unroll
            for (int t = 0; t < 2; ++t)
#pragma unroll
                for (int r = 0; r < 16; ++r) sacc[t][r] = 0.f;

            bf16x8 kf[2][4];
#pragma unroll
            for (int t = 0; t < 2; ++t)
#pragma unroll
                for (int c = 0; c < 4; ++c) {
                    int r = t * 32 + lq;
                    kf[t][c] = *(const bf16x8*)
                        &lk[(r << 6) + ((c * 16 + hi * 8) ^ ((r & 7) << 3))];
                }
            __builtin_amdgcn_s_setprio(1);
#pragma unroll
            for (int c = 0; c < 4; ++c) {
                sacc[0] = __builtin_amdgcn_mfma_f32_32x32x16_bf16(kf[0][c], qbf[c], sacc[0], 0, 0, 0);
                sacc[1] = __builtin_amdgcn_mfma_f32_32x32x16_bf16(kf[1][c], qbf[c], sacc[1], 0, 0, 0);
            }
            __builtin_amdgcn_s_setprio(0);

            // ---- V frags from LDS (latency hides under softmax) ----
            bf16x8 vf[2][4];
#pragma unroll
            for (int dt = 0; dt < 2; ++dt)
#pragma unroll
                for (int ks = 0; ks < 4; ++ks) {
                    int d = dt * 32 + lq;
                    vf[dt][ks] = *(const bf16x8*)
                        &lv[(d << 6) + ((ks * 16 + hi * 8) ^ ((d & 7) << 3))];
                }

            float pv[32];
#pragma unroll
            for (int t = 0; t < 2; ++t)
#pragma unroll
                for (int r = 0; r < 16; ++r) pv[t * 16 + r] = sacc[t][r];

            // ---- causal mask: only the wave's diagonal tile ----
            if (k0 + 63 > wlo) {
#pragma unroll
                for (int t = 0; t < 2; ++t)
#pragma unroll
                    for (int r = 0; r < 16; ++r) {
                        int key = k0 + 32 * t + (r & 3) + 8 * (r >> 2) + 4 * hi;
                        if (key > qrow) pv[t * 16 + r] = -3.0e38f;
                    }
            }

            // ---- p = exp2(s) (cosine-bounded, no max shift) ----
#pragma unroll
            for (int r = 0; r < 32; ++r)
                pv[r] = __builtin_amdgcn_exp2f(pv[r]);

            // ---- lsum += row sum ----
            float ts[16];
#pragma unroll
            for (int r = 0; r < 16; ++r) ts[r] = pv[r] + pv[r + 16];
#pragma unroll
            for (int r = 0; r < 8; ++r) ts[r] += ts[r + 8];
#pragma unroll
            for (int r = 0; r < 4; ++r) ts[r] += ts[r + 4];
            float ps = (ts[0] + ts[1]) + (ts[2] + ts[3]);
            ps += __shfl_xor(ps, 32);
            lsum += ps;

            // ---- repack P -> B-fragments via v_permlane32_swap_b32 ----
            u32x4 paw[4];
#pragma unroll
            for (int ks = 0; ks < 4; ++ks) {
                const int t = ks >> 1;
                const int b0 = (ks & 1) * 8;
#pragma unroll
                for (int m = 0; m < 2; ++m) {
                    unsigned a = cvt_pk(pv[t * 16 + b0 + 2 * m], pv[t * 16 + b0 + 2 * m + 1]);
                    unsigned b = cvt_pk(pv[t * 16 + b0 + 2 * m + 4], pv[t * 16 + b0 + 2 * m + 5]);
                    asm("v_permlane32_swap_b32 %0, %1" : "+v"(a), "+v"(b));
                    paw[ks][m]     = a;
                    paw[ks][m + 2] = b;
                }
            }

            // ---- O' += Vt x P ----
            __builtin_amdgcn_s_setprio(1);
#pragma unroll
            for (int dt = 0; dt < 2; ++dt)
#pragma unroll
                for (int ks = 0; ks < 4; ++ks) {
                    bf16x8 pa = __builtin_bit_cast(bf16x8, paw[ks]);
                    oacc[dt] = __builtin_amdgcn_mfma_f32_32x32x16_bf16(vf[dt][ks], pa, oacc[dt], 0, 0, 0);
                }
            __builtin_amdgcn_s_setprio(0);
        }
        cur = (cur == 2) ? 0 : cur + 1;
    }

    // ---- epilogue: out[q][d] = O'/lsum ----
    float inv = 1.0f / lsum;
    size_t rb = ((size_t)bh * SEQ + (size_t)qrow) * DIM;
#pragma unroll
    for (int dt = 0; dt < 2; ++dt)
#pragma unroll
        for (int g4 = 0; g4 < 4; ++g4) {
            float4 o4;
            o4.x = oacc[dt][4 * g4 + 0] * inv;
            o4.y = oacc[dt][4 * g4 + 1] * inv;
            o4.z = oacc[dt][4 * g4 + 2] * inv;
            o4.w = oacc[dt][4 * g4 + 3] * inv;
            *(float4*)(out + rb + dt * 32 + 8 * g4 + 4 * hi) = o4;
        }
}

// ---------------------------------------------------------------------------
extern "C" void kernel_launch(void* const* d_in, const int* in_sizes, int n_in,
                              void* d_out, int out_size, void* d_ws, size_t ws_size,
                              hipStream_t stream)
{
    const float* Q  = (const float*)d_in[0];
    const float* K  = (const float*)d_in[1];
    const float* V  = (const float*)d_in[2];
    const float* qs = (const float*)d_in[3];
    float* out = (float*)d_out;

    const size_t nElem = (size_t)BATCH * HEADS * SEQ * DIM;
    short* Kn = (short*)d_ws;
    short* Vt = Kn + nElem;

    {
        long long rows = (long long)BATCH * HEADS * SEQ;
        norm_k<<<(int)(rows / 16), 256, 0, stream>>>(K, Kn);
    }
    {
        dim3 grid(SEQ / 64, BATCH * HEADS);
        transpose_v<<<grid, 256, 0, stream>>>(V, Vt);
    }
    {
        // 1024 blocks (16 qb x 64 bh): 3 co-resident/CU + backfill pool
        attn_fwd<<<(SEQ / 128) * BATCH * HEADS, 256, 0, stream>>>(Q, qs, Kn, Vt, out);
    }
}

// Round 15
// 78.505 us; speedup vs baseline: 1.4941x; 1.0643x over previous
//
#include <hip/hip_runtime.h>

// ScaledDotProductAttention: causal cosine attention.
// B=4 H=16 N=2048 D=64, fp32 in/out, bf16 MFMA compute.
//
// Round 15: r10's inner loop VERBATIM (best: 68us, 3.4k cy/iter at 2-deep
// overlap). Only changes:
//  (1) balanced qb map: co-dispatched pair {i,i+256} sums to qb=7 -> every
//      CU runs 36 iters (r10's heavy-first gave worst-CU 48 = the wall;
//      48x3.4k = 163k cy matched r10's wall exactly). r12 tested this
//      confounded with KVBLK=128 which destroyed the 2-deep overlap.
//  (2) prep fused into one kernel (K-norm + V-transpose per 64-tile).
//  - QBLK=256 (8 waves x 32 q-rows), KVBLK=64, grid 512 = 2 blocks/CU.
//  - K,V pre-swizzled (elem ^= (row&7)<<3), gload_lds(16B), triple-buffer,
//    counted vmcnt (2-ahead: 2/1/0 per-wave... 8/4/0 block-wide), raw bars.
//  - no-max softmax: scores cosine-bounded (|s| <= g*log2e ~31.7) ->
//    p = exp2(s) directly, exact by shift-invariance.
//  - swapped-operand MFMA, cvt_pk + permlane32_swap P repack.

#define BATCH 4
#define HEADS 16
#define SEQ   2048
#define DIM   64
#define EPS   1e-8f
#define LOG2E 1.44269504088896340736f

typedef short bf16x8 __attribute__((ext_vector_type(8)));
typedef short s16x4  __attribute__((ext_vector_type(4)));
typedef float fx16   __attribute__((ext_vector_type(16)));
typedef unsigned int u32x4 __attribute__((ext_vector_type(4)));

static __device__ __forceinline__ short f2bf(float x) {
    unsigned u = __float_as_uint(x);
    unsigned r = (u + 0x7fffu + ((u >> 16) & 1u)) >> 16;   // RNE
    return (short)r;
}
static __device__ __forceinline__ unsigned cvt_pk(float lo, float hi) {
    unsigned r;
    asm("v_cvt_pk_bf16_f32 %0, %1, %2" : "=v"(r) : "v"(lo), "v"(hi));
    return r;
}
static __device__ __forceinline__ void gload_lds16(const short* g, short* l) {
    __builtin_amdgcn_global_load_lds(
        (const __attribute__((address_space(1))) void*)g,
        (__attribute__((address_space(3))) void*)l, 16, 0, 0);
}

// ---------------------------------------------------------------------------
// Fused prep: per (64-row tile nt, bh):
//   Kn[bh][nt][r][e ^ ((r&7)<<3)] = bf16(K_hat[bh][nt*64+r][e])
//   Vt[bh][nt][d][k ^ ((d&7)<<3)] = bf16(V[bh][nt*64+k][d])
// ---------------------------------------------------------------------------
#define TLDS 68

__global__ __launch_bounds__(256) void prep_kv(
    const float* __restrict__ K, const float* __restrict__ V,
    short* __restrict__ Kn, short* __restrict__ Vt)
{
    const int nt = blockIdx.x;
    const int bh = blockIdx.y;
    const int tid = threadIdx.x;

    // ---- K: L2-normalize 64 rows (16-lane group per row, 4 passes) ----
    const float* Kb = K + ((size_t)bh * SEQ + (size_t)nt * 64) * DIM;
    short* Kno = Kn + ((size_t)bh << 17) + (nt << 12);
    const int c4 = (tid & 15) * 4;
#pragma unroll
    for (int i = 0; i < 4; ++i) {
        const int r = i * 16 + (tid >> 4);
        float4 v = *(const float4*)(Kb + (size_t)r * DIM + c4);
        float ss = v.x * v.x + v.y * v.y + v.z * v.z + v.w * v.w;
        ss += __shfl_xor(ss, 1);
        ss += __shfl_xor(ss, 2);
        ss += __shfl_xor(ss, 4);
        ss += __shfl_xor(ss, 8);
        float s = 1.0f / (sqrtf(ss) + EPS);
        s16x4 o;
        o[0] = f2bf(v.x * s);
        o[1] = f2bf(v.y * s);
        o[2] = f2bf(v.z * s);
        o[3] = f2bf(v.w * s);
        *(s16x4*)(Kno + (r << 6) + (c4 ^ ((r & 7) << 3))) = o;
    }

    // ---- V: transpose 64x64 tile via LDS ----
    const float* Vb = V + ((size_t)bh * SEQ + (size_t)nt * 64) * DIM;
    short* Vo = Vt + ((size_t)bh << 17) + (nt << 12);
    __shared__ short lds[DIM * TLDS];
    const int cg = tid & 15;
    const int rr = tid >> 4;
#pragma unroll
    for (int i = 0; i < 4; ++i) {
        int n  = rr + i * 16;
        int d0 = cg * 4;
        float4 v = *(const float4*)(Vb + (size_t)n * DIM + d0);
        lds[(d0 + 0) * TLDS + n] = f2bf(v.x);
        lds[(d0 + 1) * TLDS + n] = f2bf(v.y);
        lds[(d0 + 2) * TLDS + n] = f2bf(v.z);
        lds[(d0 + 3) * TLDS + n] = f2bf(v.w);
    }
    __syncthreads();
#pragma unroll
    for (int i = 0; i < 4; ++i) {
        int d  = rr + i * 16;
        int nl = cg * 4;
        s16x4 o;
        o[0] = lds[d * TLDS + nl + 0];
        o[1] = lds[d * TLDS + nl + 1];
        o[2] = lds[d * TLDS + nl + 2];
        o[3] = lds[d * TLDS + nl + 3];
        *(s16x4*)(Vo + (d << 6) + (nl ^ ((d & 7) << 3))) = o;
    }
}

// ---------------------------------------------------------------------------
// Flash attention. 512 threads = 8 waves, QBLK=256, KVBLK=64.
// Grid 512 = 2 blocks/CU; co-dispatched pair {i, i+256} has qb summing to 7
// -> every CU gets exactly 36 iterations. Triple-buffered stage, 2 tiles
// ahead, counted vmcnt.
//
// mfma_f32_32x32x16_bf16 layouts:
//   A: row = lane&31, k = (lane>>5)*8 + j
//   B: col = lane&31, k = (lane>>5)*8 + j
//   C/D: col = lane&31, row = (reg&3) + 8*(reg>>2) + 4*(lane>>5)
// ---------------------------------------------------------------------------
__global__ __launch_bounds__(512) void attn_fwd(
    const float* __restrict__ Q, const float* __restrict__ scale,
    const short* __restrict__ Kn, const short* __restrict__ Vt,
    float* __restrict__ out)
{
    const int lid = blockIdx.x;                       // 0..511
    // balanced pairing: {lid, lid+256} share a CU slot, qb sums to 7
    const int q2  = lid >> 6;                         // 0..7
    const int qb  = (lid < 256) ? (7 - q2) : (q2 - 4);
    const int bh  = (lid & 7) * 8 + ((lid >> 3) & 7); // XCD lid%8 owns bh/8
    const int tid = threadIdx.x;
    const int w   = tid >> 6;                         // wave 0..7
    const int l   = tid & 63;
    const int lq  = l & 31;
    const int hi  = l >> 5;

    const short* Kb = Kn + ((size_t)bh << 17);
    const short* Vb = Vt + ((size_t)bh << 17);
    const float  g  = scale[bh & (HEADS - 1)];

    __shared__ __align__(16) short ldsK[3][64 * 64];
    __shared__ __align__(16) short ldsV[3][64 * 64];

    const int toff = tid * 8;   // 512 thr x 8 shorts = full 4096-short tile

    const int wlo  = qb * 256 + w * 32;   // wave's first q-row
    const int whi  = wlo + 31;
    const int qrow = wlo + lq;
    const int nkt  = 4 * qb + 4;

    // ---- Q loads FIRST (their use-wait drains before the steady loop) ----
    const float* Qrow = Q + ((size_t)bh * SEQ + qrow) * DIM;
    float qv[4][8];
#pragma unroll
    for (int c = 0; c < 4; ++c) {
        float4 a = *(const float4*)(Qrow + c * 16 + hi * 8);
        float4 b = *(const float4*)(Qrow + c * 16 + hi * 8 + 4);
        qv[c][0] = a.x; qv[c][1] = a.y; qv[c][2] = a.z; qv[c][3] = a.w;
        qv[c][4] = b.x; qv[c][5] = b.y; qv[c][6] = b.z; qv[c][7] = b.w;
    }

    // ---- prologue: stage tiles 0 and 1 ----
    gload_lds16(Kb + toff,        &ldsK[0][toff]);
    gload_lds16(Vb + toff,        &ldsV[0][toff]);
    gload_lds16(Kb + 4096 + toff, &ldsK[1][toff]);
    gload_lds16(Vb + 4096 + toff, &ldsV[1][toff]);

    // ---- fused Q-norm (overlaps stage latency) ----
    float ss = 0.f;
#pragma unroll
    for (int c = 0; c < 4; ++c)
#pragma unroll
        for (int jj = 0; jj < 8; ++jj) ss += qv[c][jj] * qv[c][jj];
    ss += __shfl_xor(ss, 32);
    const float sc = g * LOG2E / (sqrtf(ss) + EPS);

    bf16x8 qbf[4];
#pragma unroll
    for (int c = 0; c < 4; ++c) {
        u32x4 wds;
#pragma unroll
        for (int m = 0; m < 4; ++m)
            wds[m] = cvt_pk(qv[c][2 * m] * sc, qv[c][2 * m + 1] * sc);
        qbf[c] = __builtin_bit_cast(bf16x8, wds);
    }

    fx16 oacc[2];
#pragma unroll
    for (int dt = 0; dt < 2; ++dt)
#pragma unroll
        for (int r = 0; r < 16; ++r) oacc[dt][r] = 0.f;
    float lsum = 0.f;

    int cur = 0;   // kt % 3
    for (int kt = 0; kt < nkt; ++kt) {
        // bar A: every wave finished compute(kt-1); buf[(kt+2)%3] is free.
        __builtin_amdgcn_s_barrier();

        if (kt + 2 < nkt) {
            int nb = cur + 2; if (nb >= 3) nb -= 3;
            const short* gK = Kb + (size_t)(kt + 2) * 4096;
            const short* gV = Vb + (size_t)(kt + 2) * 4096;
            gload_lds16(gK + toff, &ldsK[nb][toff]);
            gload_lds16(gV + toff, &ldsV[nb][toff]);
            // own stage(kt) done; stages (kt+1),(kt+2) stay in flight
            asm volatile("s_waitcnt vmcnt(4)" ::: "memory");
        } else if (kt + 1 < nkt) {
            asm volatile("s_waitcnt vmcnt(2)" ::: "memory");
        } else {
            asm volatile("s_waitcnt vmcnt(0)" ::: "memory");
        }
        // bar B: all waves' stage(kt) slices visible
        __builtin_amdgcn_s_barrier();

        const int k0 = kt * 64;
        if (k0 <= whi) {   // wave-uniform causal skip (barriers outside)
            const short* lk = ldsK[cur];
            const short* lv = ldsV[cur];

            // ---- K frags from LDS (swizzled), S' = K x Q^T ----
            fx16 sacc[2];
#pragma unroll
            for (int t = 0; t < 2; ++t)
#pragma unroll
                for (int r = 0; r < 16; ++r) sacc[t][r] = 0.f;

            bf16x8 kf[2][4];
#pragma unroll
            for (int t = 0; t < 2; ++t)
#pragma unroll
                for (int c = 0; c < 4; ++c) {
                    int r = t * 32 + lq;
                    kf[t][c] = *(const bf16x8*)
                        &lk[(r << 6) + ((c * 16 + hi * 8) ^ ((r & 7) << 3))];
                }
            __builtin_amdgcn_s_setprio(1);
#pragma unroll
            for (int c = 0; c < 4; ++c) {
                sacc[0] = __builtin_amdgcn_mfma_f32_32x32x16_bf16(kf[0][c], qbf[c], sacc[0], 0, 0, 0);
                sacc[1] = __builtin_amdgcn_mfma_f32_32x32x16_bf16(kf[1][c], qbf[c], sacc[1], 0, 0, 0);
            }
            __builtin_amdgcn_s_setprio(0);

            // ---- V frags from LDS (latency hides under softmax) ----
            bf16x8 vf[2][4];
#pragma unroll
            for (int dt = 0; dt < 2; ++dt)
#pragma unroll
                for (int ks = 0; ks < 4; ++ks) {
                    int d = dt * 32 + lq;
                    vf[dt][ks] = *(const bf16x8*)
                        &lv[(d << 6) + ((ks * 16 + hi * 8) ^ ((d & 7) << 3))];
                }

            float pv[32];
#pragma unroll
            for (int t = 0; t < 2; ++t)
#pragma unroll
                for (int r = 0; r < 16; ++r) pv[t * 16 + r] = sacc[t][r];

            // ---- causal mask: only the wave's diagonal tile ----
            if (k0 + 63 > wlo) {
#pragma unroll
                for (int t = 0; t < 2; ++t)
#pragma unroll
                    for (int r = 0; r < 16; ++r) {
                        int key = k0 + 32 * t + (r & 3) + 8 * (r >> 2) + 4 * hi;
                        if (key > qrow) pv[t * 16 + r] = -3.0e38f;
                    }
            }

            // ---- p = exp2(s) (cosine-bounded, no max shift) ----
#pragma unroll
            for (int r = 0; r < 32; ++r)
                pv[r] = __builtin_amdgcn_exp2f(pv[r]);

            // ---- lsum += row sum ----
            float ts[16];
#pragma unroll
            for (int r = 0; r < 16; ++r) ts[r] = pv[r] + pv[r + 16];
#pragma unroll
            for (int r = 0; r < 8; ++r) ts[r] += ts[r + 8];
#pragma unroll
            for (int r = 0; r < 4; ++r) ts[r] += ts[r + 4];
            float ps = (ts[0] + ts[1]) + (ts[2] + ts[3]);
            ps += __shfl_xor(ps, 32);
            lsum += ps;

            // ---- repack P -> B-fragments via v_permlane32_swap_b32 ----
            u32x4 paw[4];
#pragma unroll
            for (int ks = 0; ks < 4; ++ks) {
                const int t = ks >> 1;
                const int b0 = (ks & 1) * 8;
#pragma unroll
                for (int m = 0; m < 2; ++m) {
                    unsigned a = cvt_pk(pv[t * 16 + b0 + 2 * m], pv[t * 16 + b0 + 2 * m + 1]);
                    unsigned b = cvt_pk(pv[t * 16 + b0 + 2 * m + 4], pv[t * 16 + b0 + 2 * m + 5]);
                    asm("v_permlane32_swap_b32 %0, %1" : "+v"(a), "+v"(b));
                    paw[ks][m]     = a;
                    paw[ks][m + 2] = b;
                }
            }

            // ---- O' += Vt x P ----
            __builtin_amdgcn_s_setprio(1);
#pragma unroll
            for (int dt = 0; dt < 2; ++dt)
#pragma unroll
                for (int ks = 0; ks < 4; ++ks) {
                    bf16x8 pa = __builtin_bit_cast(bf16x8, paw[ks]);
                    oacc[dt] = __builtin_amdgcn_mfma_f32_32x32x16_bf16(vf[dt][ks], pa, oacc[dt], 0, 0, 0);
                }
            __builtin_amdgcn_s_setprio(0);
        }
        cur = (cur == 2) ? 0 : cur + 1;
    }

    // ---- epilogue: out[q][d] = O'/lsum ----
    float inv = 1.0f / lsum;
    size_t rb = ((size_t)bh * SEQ + (size_t)qrow) * DIM;
#pragma unroll
    for (int dt = 0; dt < 2; ++dt)
#pragma unroll
        for (int g4 = 0; g4 < 4; ++g4) {
            float4 o4;
            o4.x = oacc[dt][4 * g4 + 0] * inv;
            o4.y = oacc[dt][4 * g4 + 1] * inv;
            o4.z = oacc[dt][4 * g4 + 2] * inv;
            o4.w = oacc[dt][4 * g4 + 3] * inv;
            *(float4*)(out + rb + dt * 32 + 8 * g4 + 4 * hi) = o4;
        }
}

// ---------------------------------------------------------------------------
extern "C" void kernel_launch(void* const* d_in, const int* in_sizes, int n_in,
                              void* d_out, int out_size, void* d_ws, size_t ws_size,
                              hipStream_t stream)
{
    const float* Q  = (const float*)d_in[0];
    const float* K  = (const float*)d_in[1];
    const float* V  = (const float*)d_in[2];
    const float* qs = (const float*)d_in[3];
    float* out = (float*)d_out;

    const size_t nElem = (size_t)BATCH * HEADS * SEQ * DIM;
    short* Kn = (short*)d_ws;
    short* Vt = Kn + nElem;

    {
        dim3 grid(SEQ / 64, BATCH * HEADS);
        prep_kv<<<grid, 256, 0, stream>>>(K, V, Kn, Vt);
    }
    {
        // 512 blocks = 2/CU, pair {i,i+256} balanced to 36 iters per CU
        attn_fwd<<<(SEQ / 256) * BATCH * HEADS, 512, 0, stream>>>(Q, qs, Kn, Vt, out);
    }
}